// Round 3
// baseline (63.893 us; speedup 1.0000x reference)
//
#include <hip/hip_runtime.h>
#include <math.h>

#define H_DIM 128
#define W_DIM 128
#define BATCH 8
#define NPIX (H_DIM * W_DIM)
#define INF_I (1 << 28)
#define ROWS_PER_BLOCK 4
#define NBLOCKS (H_DIM / ROWS_PER_BLOCK)   // 32
#define NTHREADS 512

// Fused distance transform: one kernel, 32 blocks x 512 threads.
// Each block rebuilds the batch-union boundary mask (512 KB L2-resident read,
// latency-hidden by 8 waves) and computes 4 output rows via separable DT.
__global__ __launch_bounds__(NTHREADS) void fused_dt_kernel(
    const float* __restrict__ fm, float* __restrict__ out) {
    const int tid = threadIdx.x;           // 0..511

    __shared__ unsigned char maskS[NPIX];  // 16 KB boundary mask
    __shared__ int gpart[4][W_DIM];
    __shared__ int gS[W_DIM];
    __shared__ int bpart[4][W_DIM];
    __shared__ float distS[W_DIM];

    // ---- Mask: 8 chunks x 512 threads x 4 pixels; OR over 8 batches ----
    const float4* fm4 = (const float4*)fm;   // 4096 float4 per image
    #pragma unroll
    for (int q = 0; q < 8; ++q) {
        const int idx4 = q * NTHREADS + tid;
        bool m0 = false, m1 = false, m2 = false, m3 = false;
        #pragma unroll
        for (int b = 0; b < BATCH; ++b) {
            float4 v = fm4[b * 4096 + idx4];
            m0 |= v.x > 0.5f;
            m1 |= v.y > 0.5f;
            m2 |= v.z > 0.5f;
            m3 |= v.w > 0.5f;
        }
        uchar4 mm;
        mm.x = (unsigned char)m0;
        mm.y = (unsigned char)m1;
        mm.z = (unsigned char)m2;
        mm.w = (unsigned char)m3;
        ((uchar4*)maskS)[idx4] = mm;
    }
    __syncthreads();

    const int w = tid & 127;          // column / j index
    const int quarter = tid >> 7;     // 0..3: range split for both passes

    for (int r = 0; r < ROWS_PER_BLOCK; ++r) {
        const int i = blockIdx.x * ROWS_PER_BLOCK + r;   // output row

        // ---- Column DT: g[w] = min_h (mask[h][w] ? (i-h)^2 : INF) ----
        {
            int g = INF_I;
            const int h0 = quarter * 32;
            #pragma unroll 4
            for (int hh = 0; hh < 32; ++hh) {
                const int h = h0 + hh;
                const int d = i - h;
                if (maskS[h * W_DIM + w]) g = min(g, d * d);
            }
            gpart[quarter][w] = g;
        }
        __syncthreads();
        if (tid < W_DIM)
            gS[tid] = min(min(gpart[0][tid], gpart[1][tid]),
                          min(gpart[2][tid], gpart[3][tid]));
        __syncthreads();

        // ---- Row DT: best[j] = min_w (g[w] + (j-w)^2), j = w ----
        {
            int best = INF_I;
            const int w0 = quarter * 32;
            #pragma unroll 4
            for (int ww = 0; ww < 32; ++ww) {
                const int wc = w0 + ww;
                const int d = w - wc;
                best = min(best, gS[wc] + d * d);   // <= 2^28 + 16129, no overflow
            }
            bpart[quarter][w] = best;
        }
        __syncthreads();
        if (tid < W_DIM) {
            const int best = min(min(bpart[0][tid], bpart[1][tid]),
                                 min(bpart[2][tid], bpart[3][tid]));
            distS[tid] = (best >= INF_I) ? INFINITY : sqrtf((float)best);
        }
        __syncthreads();

        // ---- Write row i for 8 batches: quarter covers 2 batches each ----
        const float v = distS[w];
        #pragma unroll
        for (int k = 0; k < 2; ++k) {
            const int b = quarter * 2 + k;
            out[b * NPIX + i * W_DIM + w] = v;
        }
        // no trailing sync needed: next iteration's first write (gpart) is a
        // different array than distS, and sync-1 of next iter orders it.
    }
}

extern "C" void kernel_launch(void* const* d_in, const int* in_sizes, int n_in,
                              void* d_out, int out_size, void* d_ws, size_t ws_size,
                              hipStream_t stream) {
    const float* fm = (const float*)d_in[0];
    float* out = (float*)d_out;
    fused_dt_kernel<<<NBLOCKS, NTHREADS, 0, stream>>>(fm, out);
}

// Round 4
// 58.262 us; speedup vs baseline: 1.0966x; 1.0966x over previous
//
#include <hip/hip_runtime.h>
#include <math.h>

#define H_DIM 128
#define W_DIM 128
#define BATCH 8
#define NPIX (H_DIM * W_DIM)
#define INF_I (1 << 28)

// K1: boundary mask unioned over batch, 64 blocks x 256 threads.
// Block p covers 64 float4-pixel-groups; threads = (64 pixels x 4 batch-pairs).
// Each thread reads 2 float4 (32 B); partials OR'd through LDS. Per-block
// ingest 8 KB -> latency-bound ~0.5 us.
__global__ __launch_bounds__(256) void mask_kernel(const float* __restrict__ fm,
                                                   unsigned int* __restrict__ mask) {
    const int tid = threadIdx.x;
    const int p = tid & 63;                  // pixel-group within block
    const int bp = tid >> 6;                 // 0..3: batch pair
    const int idx4 = blockIdx.x * 64 + p;    // float4 index within one image
    const float4* fm4 = (const float4*)fm;   // 4096 float4 per image

    __shared__ unsigned int part[4][64];

    float4 v0 = fm4[(2 * bp) * 4096 + idx4];
    float4 v1 = fm4[(2 * bp + 1) * 4096 + idx4];
    // pack 4 pixel flags as bytes 0x00/0x01 in a dword
    unsigned int m = 0;
    m |= (unsigned int)((v0.x > 0.5f) | (v1.x > 0.5f));
    m |= (unsigned int)((v0.y > 0.5f) | (v1.y > 0.5f)) << 8;
    m |= (unsigned int)((v0.z > 0.5f) | (v1.z > 0.5f)) << 16;
    m |= (unsigned int)((v0.w > 0.5f) | (v1.w > 0.5f)) << 24;
    part[bp][p] = m;
    __syncthreads();

    if (tid < 64)
        mask[idx4] = part[0][p] | part[1][p] | part[2][p] | part[3][p];
}

// K2: separable distance transform. One block per output row i (128 blocks).
// Per-block ingest is only the 16 KB mask (L2-resident after K1).
__global__ __launch_bounds__(256) void dt_kernel(const unsigned char* __restrict__ mask,
                                                 float* __restrict__ out) {
    const int i = blockIdx.x;        // output row
    const int tid = threadIdx.x;     // 0..255

    __shared__ unsigned char maskS[NPIX];   // 16 KB
    __shared__ int gpart[2][W_DIM];
    __shared__ int gS[W_DIM];
    __shared__ int bpart[2][W_DIM];
    __shared__ float distS[W_DIM];

    // Load mask 16 KB -> LDS: 4 x 4 KB coalesced float4.
    const float4* m4 = (const float4*)mask;
    #pragma unroll
    for (int q = 0; q < 4; ++q)
        ((float4*)maskS)[q * 256 + tid] = m4[q * 256 + tid];
    __syncthreads();

    const int w = tid & 127;
    const int half = tid >> 7;       // 0: range [0,64), 1: [64,128)

    // Pass B: column DT. g[w] = min_h (mask[h][w] ? (i-h)^2 : INF), h split.
    {
        int g = INF_I;
        const int h0 = half * 64;
        #pragma unroll 4
        for (int hh = 0; hh < 64; ++hh) {
            const int h = h0 + hh;
            const int d = i - h;
            if (maskS[h * W_DIM + w]) g = min(g, d * d);
        }
        gpart[half][w] = g;
    }
    __syncthreads();
    if (tid < W_DIM) gS[tid] = min(gpart[0][tid], gpart[1][tid]);
    __syncthreads();

    // Pass C: row DT. best[j] = min_w (g[w] + (j-w)^2), w split.
    {
        const int j = w;
        int best = INF_I;
        const int w0 = half * 64;
        #pragma unroll 4
        for (int ww = 0; ww < 64; ++ww) {
            const int wc = w0 + ww;
            const int d = j - wc;
            best = min(best, gS[wc] + d * d);   // max = 2^28 + 16129, no overflow
        }
        bpart[half][j] = best;
    }
    __syncthreads();
    if (tid < W_DIM) {
        const int best = min(bpart[0][tid], bpart[1][tid]);
        distS[tid] = (best >= INF_I) ? INFINITY : sqrtf((float)best);
    }
    __syncthreads();

    // Write row i broadcast across 8 batch images, coalesced.
    const int j = tid & 127;
    const int bh = tid >> 7;
    const float v = distS[j];
    #pragma unroll
    for (int k = 0; k < 4; ++k) {
        const int b = bh * 4 + k;
        out[b * NPIX + i * W_DIM + j] = v;
    }
}

extern "C" void kernel_launch(void* const* d_in, const int* in_sizes, int n_in,
                              void* d_out, int out_size, void* d_ws, size_t ws_size,
                              hipStream_t stream) {
    const float* fm = (const float*)d_in[0];
    float* out = (float*)d_out;
    unsigned int* mask = (unsigned int*)d_ws;   // 16 KB of workspace

    mask_kernel<<<64, 256, 0, stream>>>(fm, mask);
    dt_kernel<<<H_DIM, 256, 0, stream>>>((const unsigned char*)mask, out);
}